// Round 1
// baseline (118.498 us; speedup 1.0000x reference)
//
#include <hip/hip_runtime.h>
#include <hip/hip_bf16.h>

// CustomBernsteinLayer: out[b,o] = sum_{i,k} ber[b,i,k] * (coeffs[o,i,k]*weights[o,i])
// ber[b,i,k] = (1+tanh(x))^k * (1-tanh(x))^(8-k)
// => bf16 MFMA GEMM  M=16384, N=256, K=2304, A generated on the fly.

#define BDIM 16384
#define IDIM 256
#define ODIM 256
#define NK 9                      // ORDER+1
#define ICHUNK 64                 // i-values per K-chunk
#define NCHUNK (IDIM / ICHUNK)    // 4
#define NSTEP (NCHUNK * NK)       // 36 K-steps of 64
#define STEP_ELEMS (ODIM * ICHUNK) // 16384 bf16 elements (32 KB) per step block

typedef short short8 __attribute__((ext_vector_type(8)));
typedef float floatx4 __attribute__((ext_vector_type(4)));

static __device__ __forceinline__ ushort f2bf(float f) {
    // round-to-nearest-even f32 -> bf16 (inputs are finite; no NaN path needed)
    union { float f; unsigned int u; } x;
    x.f = f;
    unsigned int r = x.u + 0x7FFFu + ((x.u >> 16) & 1u);
    return (ushort)(r >> 16);
}

// ---------------------------------------------------------------------------
// prep: wc[o, kappa] = bf16(coeffs[o,i,k] * weights[o,i]) in fragment-ready
// layout: for K-step (ic,k): 32KB block, element offset
//   (((o>>4)*2 + s)*64 + (o&15) + quad*16)*8 + j
// with i_local = i & 63, s = i_local>>5, quad = (i_local>>3)&3, j = i_local&7.
// This makes GEMM B-staging a straight linear copy and ds_read_b128 per frag.
// ---------------------------------------------------------------------------
__global__ void prep_wc_kernel(const float* __restrict__ weights,
                               const float* __restrict__ coeffs,
                               ushort* __restrict__ wc) {
    int idx = blockIdx.x * 256 + threadIdx.x;   // idx = o*256 + i
    int o = idx >> 8;
    int i = idx & 255;
    float wv = weights[idx];
    int ic = i >> 6;
    int il = i & 63;
    int s    = il >> 5;
    int quad = (il >> 3) & 3;
    int j    = il & 7;
    int base = ((((o >> 4) * 2 + s) * 64) + (o & 15) + quad * 16) * 8 + j;
    const float* cp = coeffs + idx * NK;
#pragma unroll
    for (int k = 0; k < NK; ++k) {
        int step = ic * NK + k;
        wc[step * STEP_ELEMS + base] = f2bf(cp[k] * wv);
    }
}

// ---------------------------------------------------------------------------
// GEMM: BM=64, BN=256 (all of O), 256 threads = 4 waves, each wave a 64x64
// output quadrant as 4(M) x 4(N) mfma_f32_16x16x32_bf16 tiles.
// A-tile generated in-register: per i-chunk keep p=(1-t)^8, r=(1+t)/(1-t);
// per order k emit bf16(p) into LDS fragments, p *= r.
// B-tile staged 32KB/step via global_load_lds width=16 (linear layout).
// ---------------------------------------------------------------------------
__global__ __launch_bounds__(256) void bern_gemm(const float* __restrict__ x,
                                                 const ushort* __restrict__ wc,
                                                 float* __restrict__ out) {
    __shared__ ushort A_lds[2 * 4 * 64 * 8];   // [s][m][lane][8]  = 8 KB
    __shared__ ushort B_lds[STEP_ELEMS];       // 32 KB

    const int tid  = threadIdx.x;
    const int wave = tid >> 6;
    const int lane = tid & 63;
    const int row0 = blockIdx.x * 64;

    // A-generation ownership: unit = (row, jg) covering i_local = jg*8..jg*8+7.
    // thread owns units tid and tid+256 -> rows tid>>3 and 32+(tid>>3).
    const int ra0 = tid >> 3;
    const int jg  = tid & 7;
    const int rows_a[2] = { ra0, 32 + ra0 };
    int aoff[2];
#pragma unroll
    for (int u = 0; u < 2; ++u) {
        int rr = rows_a[u];
        // s = jg>>2, m = rr>>4, lane_w = (rr&15) + (jg&3)*16
        aoff[u] = ((((jg >> 2) * 4 + (rr >> 4)) * 64) + (rr & 15) + (jg & 3) * 16) * 8;
    }

    floatx4 acc[4][4];
    floatx4 zero = {0.0f, 0.0f, 0.0f, 0.0f};
#pragma unroll
    for (int m = 0; m < 4; ++m)
#pragma unroll
        for (int n = 0; n < 4; ++n)
            acc[m][n] = zero;

    float p_[2][8], r_[2][8];

    for (int ic = 0; ic < NCHUNK; ++ic) {
        // ---- per-i-chunk setup: tanh once, then incremental powers ----
#pragma unroll
        for (int u = 0; u < 2; ++u) {
            const float* xp = x + (size_t)(row0 + rows_a[u]) * IDIM + ic * ICHUNK + jg * 8;
            float4 v0 = *(const float4*)(xp);
            float4 v1 = *(const float4*)(xp + 4);
            float xv[8] = {v0.x, v0.y, v0.z, v0.w, v1.x, v1.y, v1.z, v1.w};
#pragma unroll
            for (int e = 0; e < 8; ++e) {
                float xt = tanhf(xv[e]);
                xt = fminf(0.99999994f, fmaxf(-0.99999994f, xt));
                float xa = 1.0f + xt;
                float xb = 1.0f - xt;
                float t2 = xb * xb;
                float t4 = t2 * t2;
                p_[u][e] = t4 * t4;        // xb^8  (= ber at k=0)
                r_[u][e] = xa / xb;        // ratio; ber_{k+1} = ber_k * r
            }
        }

        for (int k = 0; k < NK; ++k) {
            const int step = ic * NK + k;

            // ---- A fragment emit (bf16 pack + one ds_write_b128 per unit) ----
#pragma unroll
            for (int u = 0; u < 2; ++u) {
                union { ushort us[8]; int4 v; } pk;
#pragma unroll
                for (int e = 0; e < 8; ++e) {
                    pk.us[e] = f2bf(p_[u][e]);
                    p_[u][e] *= r_[u][e];
                }
                *(int4*)&A_lds[aoff[u]] = pk.v;
            }

            // ---- B staging: 32 KB linear copy, wave-uniform base + lane*16 ----
            {
                const char* src = (const char*)(wc + (size_t)step * STEP_ELEMS);
                char* dst = (char*)B_lds;
#pragma unroll
                for (int it = 0; it < 8; ++it) {
                    int off = wave * 8192 + it * 1024 + lane * 16;   // bytes
                    __builtin_amdgcn_global_load_lds(
                        (const __attribute__((address_space(1))) void*)(src + off),
                        (__attribute__((address_space(3))) void*)(dst + off),
                        16, 0, 0);
                }
            }

            __syncthreads();

            // ---- MFMA: 2 sub-k of 32, 4x4 tiles per wave ----
#pragma unroll
            for (int s = 0; s < 2; ++s) {
                short8 af[4], bf[4];
#pragma unroll
                for (int m = 0; m < 4; ++m)
                    af[m] = *(const short8*)&A_lds[(((s * 4 + m) * 64) + lane) * 8];
#pragma unroll
                for (int n = 0; n < 4; ++n) {
                    int nglob = wave * 4 + n;
                    bf[n] = *(const short8*)&B_lds[(((nglob * 2 + s) * 64) + lane) * 8];
                }
#pragma unroll
                for (int m = 0; m < 4; ++m)
#pragma unroll
                    for (int n = 0; n < 4; ++n)
                        acc[m][n] = __builtin_amdgcn_mfma_f32_16x16x32_bf16(
                            af[m], bf[n], acc[m][n], 0, 0, 0);
            }

            __syncthreads();
        }
    }

    // ---- epilogue: C/D layout col = lane&15, row = (lane>>4)*4 + reg ----
#pragma unroll
    for (int m = 0; m < 4; ++m) {
#pragma unroll
        for (int n = 0; n < 4; ++n) {
            int col   = wave * 64 + n * 16 + (lane & 15);
            int rbase = row0 + m * 16 + (lane >> 4) * 4;
#pragma unroll
            for (int reg = 0; reg < 4; ++reg) {
                out[(size_t)(rbase + reg) * ODIM + col] = acc[m][n][reg];
            }
        }
    }
}

extern "C" void kernel_launch(void* const* d_in, const int* in_sizes, int n_in,
                              void* d_out, int out_size, void* d_ws, size_t ws_size,
                              hipStream_t stream) {
    const float* x       = (const float*)d_in[0];   // [B, I]
    const float* weights = (const float*)d_in[1];   // [O, I]
    const float* coeffs  = (const float*)d_in[2];   // [O, I, 9]
    float* out = (float*)d_out;                     // [B, O]
    ushort* wc = (ushort*)d_ws;                     // 36 * 32 KB = 1.13 MB

    // ws is re-poisoned before every launch -> wc must be rebuilt every call.
    prep_wc_kernel<<<(ODIM * IDIM) / 256, 256, 0, stream>>>(weights, coeffs, wc);
    bern_gemm<<<BDIM / 64, 256, 0, stream>>>(x, wc, out);
}

// Round 2
// 98.225 us; speedup vs baseline: 1.2064x; 1.2064x over previous
//
#include <hip/hip_runtime.h>
#include <hip/hip_bf16.h>

// CustomBernsteinLayer: out[b,o] = sum_{i,k} ber[b,i,k] * (coeffs[o,i,k]*weights[o,i])
// ber = (1+t)^k (1-t)^(8-k), t = tanh(x).  With e = exp2(2x*log2e):
//   (1-t) = 2/(e+1) = q, (1+t) = 2e/(e+1), ratio r = e, p0 = q^8, ber_{k+1} = ber_k * r.
// bf16 MFMA GEMM M=16384 N=256 K=2304; A generated on the fly; B (wc) in
// fragment-ready layout so B-frags are direct global dwordx4 loads (no LDS).

#define BDIM 16384
#define IDIM 256
#define ODIM 256
#define NK 9
#define ICHUNK 64
#define NCHUNK (IDIM / ICHUNK)     // 4
#define NSTEP (NCHUNK * NK)        // 36
#define STEP_ELEMS (ODIM * ICHUNK) // 16384 bf16 per K-step block (32 KB)

typedef short short8 __attribute__((ext_vector_type(8)));
typedef float floatx4 __attribute__((ext_vector_type(4)));

// ---------------------------------------------------------------------------
// prep: wc[step][e] = bf16(coeffs[o,i,k]*weights[o,i]) in fragment-ready
// layout: e = (((o>>4)*2 + s)*64 + (o&15) + quad*16)*8 + j,
//         il = i&63 = s*32 + quad*8 + j, step = (i>>6)*9 + k.
// One 16B chunk (fixed o,s,quad,k; j=0..7) per thread; stores fully coalesced.
// ---------------------------------------------------------------------------
__global__ __launch_bounds__(256) void prep_wc2(const float* __restrict__ weights,
                                                const float* __restrict__ coeffs,
                                                ushort* __restrict__ wc) {
    int idx  = blockIdx.x * 256 + threadIdx.x;  // 73728 chunks total
    int step = idx >> 11;                       // 2048 chunks per step
    int c    = idx & 2047;
    int big    = c >> 6;                        // (o>>4)*2 + s
    int lane_w = c & 63;                        // (o&15) + quad*16
    int o    = (big >> 1) * 16 + (lane_w & 15);
    int s    = big & 1;
    int quad = lane_w >> 4;
    int ic = step / 9;
    int k  = step - ic * 9;
    int i0 = ic * 64 + s * 32 + quad * 8;

    const float* cp = coeffs + (size_t)(o * IDIM + i0) * NK + k;   // stride NK per j
    float4 w0 = *(const float4*)(weights + o * IDIM + i0);
    float4 w1 = *(const float4*)(weights + o * IDIM + i0 + 4);
    float wv[8] = {w0.x, w0.y, w0.z, w0.w, w1.x, w1.y, w1.z, w1.w};

    union { ushort us[8]; int4 v; __hip_bfloat162 h2[4]; } pk;
#pragma unroll
    for (int j = 0; j < 8; j += 2) {
        float a = cp[(size_t)j * NK] * wv[j];
        float b = cp[(size_t)(j + 1) * NK] * wv[j + 1];
        pk.h2[j >> 1] = __float22bfloat162_rn(make_float2(a, b));
    }
    *(int4*)(wc + (size_t)step * STEP_ELEMS + (size_t)c * 8) = pk.v;
}

// ---------------------------------------------------------------------------
// GEMM: BM=64, BN=256, 256 blocks x 256 threads (4 waves), wave = 64x64 out
// via 4x4 mfma_f32_16x16x32_bf16. A in double-buffered LDS (1 barrier/step);
// B-frags loaded straight from global (L2-resident wc) into VGPRs.
// ---------------------------------------------------------------------------
__global__ __launch_bounds__(256) void bern_gemm(const float* __restrict__ x,
                                                 const ushort* __restrict__ wc,
                                                 float* __restrict__ out) {
    __shared__ ushort A_lds[2][4096];           // [buf][s][m][lane][8] = 2 x 8 KB

    const int tid  = threadIdx.x;
    const int wave = tid >> 6;
    const int lane = tid & 63;
    const int row0 = blockIdx.x * 64;

    // A-gen ownership: thread -> rows {tid>>3, 32+(tid>>3)}, il = (tid&7)*8 .. +7
    const int ra0 = tid >> 3;
    const int jg  = tid & 7;
    const int rows_a[2] = { ra0, 32 + ra0 };
    int aoff[2];
#pragma unroll
    for (int u = 0; u < 2; ++u) {
        int rr = rows_a[u];
        aoff[u] = ((((jg >> 2) * 4 + (rr >> 4)) * 64) + (rr & 15) + (jg & 3) * 16) * 8;
    }

    floatx4 acc[4][4];
    floatx4 zero = {0.0f, 0.0f, 0.0f, 0.0f};
#pragma unroll
    for (int m = 0; m < 4; ++m)
#pragma unroll
        for (int n = 0; n < 4; ++n)
            acc[m][n] = zero;

    float p_[2][8], r_[2][8];
    float4 xa0[2], xa1[2];

    // preload x for chunk 0
#pragma unroll
    for (int u = 0; u < 2; ++u) {
        const float* xp = x + (size_t)(row0 + rows_a[u]) * IDIM + jg * 8;
        xa0[u] = *(const float4*)(xp);
        xa1[u] = *(const float4*)(xp + 4);
    }

    for (int ic = 0; ic < NCHUNK; ++ic) {
        // ---- basis setup from prefetched x: r = exp2(2x*log2e), p = (2/(r+1))^8
#pragma unroll
        for (int u = 0; u < 2; ++u) {
            float xv[8] = {xa0[u].x, xa0[u].y, xa0[u].z, xa0[u].w,
                           xa1[u].x, xa1[u].y, xa1[u].z, xa1[u].w};
#pragma unroll
            for (int e = 0; e < 8; ++e) {
                float t = __builtin_amdgcn_exp2f(xv[e] * 2.8853900817779268f);
                float q = 2.0f * __builtin_amdgcn_rcpf(t + 1.0f);
                float q2 = q * q;
                float q4 = q2 * q2;
                p_[u][e] = q4 * q4;     // ber_0 = (1-t)^8
                r_[u][e] = t;           // ber_{k+1} = ber_k * r
            }
        }
        // ---- prefetch next chunk's x (in flight across 9 steps) ----
        if (ic < NCHUNK - 1) {
#pragma unroll
            for (int u = 0; u < 2; ++u) {
                const float* xp = x + (size_t)(row0 + rows_a[u]) * IDIM + (ic + 1) * ICHUNK + jg * 8;
                xa0[u] = *(const float4*)(xp);
                xa1[u] = *(const float4*)(xp + 4);
            }
        }

#pragma unroll
        for (int k = 0; k < NK; ++k) {
            const int step = ic * NK + k;
            const int buf  = step & 1;

            // ---- B fragments: direct global dwordx4, issued first ----
            short8 bfr[2][4];
            const ushort* wstep = wc + (size_t)step * STEP_ELEMS;
#pragma unroll
            for (int s = 0; s < 2; ++s)
#pragma unroll
                for (int n = 0; n < 4; ++n) {
                    int nglob = wave * 4 + n;
                    bfr[s][n] = *(const short8*)(wstep + ((nglob * 2 + s) * 64 + lane) * 8);
                }

            // ---- A fragment emit (packed bf16 cvt + ds_write_b128) ----
#pragma unroll
            for (int u = 0; u < 2; ++u) {
                union { ushort us[8]; int4 v; __hip_bfloat162 h2[4]; } pk;
#pragma unroll
                for (int e = 0; e < 8; e += 2) {
                    pk.h2[e >> 1] = __float22bfloat162_rn(make_float2(p_[u][e], p_[u][e + 1]));
                    p_[u][e]     *= r_[u][e];
                    p_[u][e + 1] *= r_[u][e + 1];
                }
                *(int4*)&A_lds[buf][aoff[u]] = pk.v;
            }

            __syncthreads();   // single barrier: A[buf] write -> read (dbuf covers WAR)

            // ---- MFMA ----
#pragma unroll
            for (int s = 0; s < 2; ++s) {
                short8 af[4];
#pragma unroll
                for (int m = 0; m < 4; ++m)
                    af[m] = *(const short8*)&A_lds[buf][((s * 4 + m) * 64 + lane) * 8];
#pragma unroll
                for (int m = 0; m < 4; ++m)
#pragma unroll
                    for (int n = 0; n < 4; ++n)
                        acc[m][n] = __builtin_amdgcn_mfma_f32_16x16x32_bf16(
                            af[m], bfr[s][n], acc[m][n], 0, 0, 0);
            }
        }
    }

    // ---- epilogue: C/D layout col = lane&15, row = (lane>>4)*4 + reg ----
#pragma unroll
    for (int m = 0; m < 4; ++m) {
#pragma unroll
        for (int n = 0; n < 4; ++n) {
            int col   = wave * 64 + n * 16 + (lane & 15);
            int rbase = row0 + m * 16 + (lane >> 4) * 4;
#pragma unroll
            for (int reg = 0; reg < 4; ++reg) {
                out[(size_t)(rbase + reg) * ODIM + col] = acc[m][n][reg];
            }
        }
    }
}

extern "C" void kernel_launch(void* const* d_in, const int* in_sizes, int n_in,
                              void* d_out, int out_size, void* d_ws, size_t ws_size,
                              hipStream_t stream) {
    const float* x       = (const float*)d_in[0];   // [B, I]
    const float* weights = (const float*)d_in[1];   // [O, I]
    const float* coeffs  = (const float*)d_in[2];   // [O, I, 9]
    float* out = (float*)d_out;                     // [B, O]
    ushort* wc = (ushort*)d_ws;                     // 36 * 32 KB = 1.13 MB

    prep_wc2<<<(NSTEP * STEP_ELEMS / 8) / 256, 256, 0, stream>>>(weights, coeffs, wc);
    bern_gemm<<<BDIM / 64, 256, 0, stream>>>(x, wc, out);
}